// Round 4
// baseline (226.217 us; speedup 1.0000x reference)
//
#include <hip/hip_runtime.h>
#include <cstdint>
#include <cstddef>

// Problem constants
#define B_    8
#define C_    256
#define H_    64
#define W_    64
#define A_    4
#define NH_   8
#define DH_   32
#define L_    1024
#define NPAIR 32
#define QKVN  768

typedef __bf16 bf16;
typedef __bf16 bf16x8 __attribute__((ext_vector_type(8)));
typedef __bf16 bf16x4 __attribute__((ext_vector_type(4)));
typedef float  f32x4  __attribute__((ext_vector_type(4)));

// dh^-0.5 * log2(e): folded into Q at projection time
#define QSCALE 0.25506866729736328f

__device__ inline f32x4 mfma16(bf16x8 a, bf16x8 b, f32x4 c) {
    return __builtin_amdgcn_mfma_f32_16x16x32_bf16(a, b, c, 0, 0, 0);
}
__device__ inline bf16x8 ld8(const bf16* p) { return *(const bf16x8*)p; }

// async global->LDS, 16B per lane; LDS dest = wave-uniform base + lane*16
__device__ inline void stage16(const bf16* g, bf16* l) {
    __builtin_amdgcn_global_load_lds(
        (const __attribute__((address_space(1))) void*)g,
        (__attribute__((address_space(3))) void*)l, 16, 0, 0);
}

// ---------------------------------------------------------------------------
// K0: fused  (a) x[B,C,H,W] f32 -> xa[pair,l,c] bf16   [blocks 0..1023]
//            (b) W_in/W_out f32 -> bf16 convert        [blocks 1024..2047]
// ---------------------------------------------------------------------------
#define NW4 (786432 / 4)
#define NO4 (262144 / 4)
__global__ __launch_bounds__(256) void k_split(const float* __restrict__ x,
                                               bf16* __restrict__ xa,
                                               const float* __restrict__ Win,
                                               const float* __restrict__ Wout,
                                               bf16* __restrict__ Winb,
                                               bf16* __restrict__ Woutb) {
    __shared__ float lds[32][257];
    int bid = blockIdx.x;
    int t = threadIdx.x;
    if (bid >= NPAIR * 32) {
        int tid = (bid - NPAIR * 32) * 256 + t;
        if (tid < NW4) {
            float4 v = ((const float4*)Win)[tid];
            bf16x4 ov = {(bf16)v.x, (bf16)v.y, (bf16)v.z, (bf16)v.w};
            ((bf16x4*)Winb)[tid] = ov;
        } else if (tid < NW4 + NO4) {
            int t2 = tid - NW4;
            float4 v = ((const float4*)Wout)[t2];
            bf16x4 ov = {(bf16)v.x, (bf16)v.y, (bf16)v.z, (bf16)v.w};
            ((bf16x4*)Woutb)[t2] = ov;
        }
        return;
    }
    int pair = bid >> 5, p = bid & 31;
    int b = pair >> 2, a = pair & 3, i = a >> 1, j = a & 1;
    int q = t & 31, csub = t >> 5;
    const float* xb = x + (size_t)b * C_ * H_ * W_ + (size_t)(i * 32 + p) * W_ + j * 32;
    for (int r = 0; r < 32; ++r) {
        int c = r * 8 + csub;
        lds[q][c] = xb[(size_t)c * H_ * W_ + q];
    }
    __syncthreads();
    bf16* xr = xa + ((size_t)pair * L_ + (size_t)p * 32) * C_;
    for (int r = 0; r < 32; ++r) {
        xr[(size_t)r * C_ + t] = (bf16)lds[r][t];
    }
}

// ---------------------------------------------------------------------------
// K1: in-projection, m97-style LDS-staged GEMM.
// Tile 128(M) x 128(N), BK=64, 4 waves 2x2, each wave 64x64 (4x4 frags).
// Epilogue: Q cols (<256) prescaled -> qk, K cols -> qk, V cols -> vT.
// grid: 32 pair x 8 mt x 6 nt = 1536
// ---------------------------------------------------------------------------
__global__ __launch_bounds__(256) void k_qkv(const bf16* __restrict__ xa,
                                             const bf16* __restrict__ Win,
                                             const float* __restrict__ bin,
                                             bf16* __restrict__ qk,
                                             bf16* __restrict__ vT) {
    __shared__ __align__(16) bf16 lA[128 * 64];
    __shared__ __align__(16) bf16 lB[128 * 64];
    int bid = blockIdx.x;
    int nt = bid % 6, mt = (bid / 6) & 7, pair = bid / 48;
    int a = pair & 3;
    int t = threadIdx.x, w = t >> 6, lane = t & 63;
    int wm = w >> 1, wn = w & 1;
    int quad = lane >> 4, l16 = lane & 15;
    int m0 = mt * 128, n0 = nt * 128;
    int r8 = lane >> 3, pc = lane & 7, jj = pc ^ r8;
    const bf16* ga = xa + (size_t)pair * L_ * C_ + (size_t)(m0 + w * 32 + r8) * C_ + jj * 8;
    const bf16* gb = Win + (size_t)a * QKVN * C_ + (size_t)(n0 + w * 32 + r8) * C_ + jj * 8;
    f32x4 acc[4][4];
#pragma unroll
    for (int fm = 0; fm < 4; ++fm)
#pragma unroll
        for (int fn = 0; fn < 4; ++fn) acc[fm][fn] = (f32x4){0.f, 0.f, 0.f, 0.f};
    for (int k0 = 0; k0 < C_; k0 += 64) {
        __syncthreads();
#pragma unroll
        for (int i = 0; i < 4; ++i) {
            stage16(ga + (size_t)(i * 8) * C_ + k0, lA + (w * 32 + i * 8) * 64);
            stage16(gb + (size_t)(i * 8) * C_ + k0, lB + (w * 32 + i * 8) * 64);
        }
        __syncthreads();
#pragma unroll
        for (int ks = 0; ks < 2; ++ks) {
            int p = (ks * 4 + quad) ^ (l16 & 7);
            bf16x8 am[4], bn[4];
#pragma unroll
            for (int f = 0; f < 4; ++f) {
                am[f] = *(const bf16x8*)&lA[(wm * 64 + f * 16 + l16) * 64 + p * 8];
                bn[f] = *(const bf16x8*)&lB[(wn * 64 + f * 16 + l16) * 64 + p * 8];
            }
#pragma unroll
            for (int fm = 0; fm < 4; ++fm)
#pragma unroll
                for (int fn = 0; fn < 4; ++fn)
                    acc[fm][fn] = mfma16(am[fm], bn[fn], acc[fm][fn]);
        }
    }
    int colbase = n0 + wn * 64;
    int mb = m0 + wm * 64;
    if (colbase < 512) {
        float sc = (colbase < 256) ? QSCALE : 1.0f;
        bf16* ob = qk + (size_t)pair * L_ * 512;
#pragma unroll
        for (int fn = 0; fn < 4; ++fn) {
            int col = colbase + fn * 16 + l16;
            float bias = bin[a * QKVN + col];
#pragma unroll
            for (int fm = 0; fm < 4; ++fm) {
                int m = mb + fm * 16 + quad * 4;
#pragma unroll
                for (int r = 0; r < 4; ++r)
                    ob[(size_t)(m + r) * 512 + col] = (bf16)((acc[fm][fn][r] + bias) * sc);
            }
        }
    } else {
        bf16* vb = vT + (size_t)pair * C_ * L_;
#pragma unroll
        for (int fn = 0; fn < 4; ++fn) {
            int e = colbase - 512 + fn * 16 + l16;
            float bias = bin[a * QKVN + colbase + fn * 16 + l16];
#pragma unroll
            for (int fm = 0; fm < 4; ++fm) {
                int m = mb + fm * 16 + quad * 4;
                bf16x4 pk = {(bf16)(acc[fm][fn][0] + bias), (bf16)(acc[fm][fn][1] + bias),
                             (bf16)(acc[fm][fn][2] + bias), (bf16)(acc[fm][fn][3] + bias)};
                *(bf16x4*)&vb[(size_t)e * L_ + m] = pk;
            }
        }
    }
}

// ---------------------------------------------------------------------------
// K2: attention. block 256 = 4 waves, same (pair, head).
// R2 structure verbatim (verified best: 67.7us): shared K/V LDS staging via
// global_load_lds, single-buffered, two __syncthreads per iter, next-tile
// stage issued right after frag reads.
// R4 deltas (VALU cut; no structural change):
//  - softmax denominator via P x ones MFMA (accS) instead of l4 VALU adds;
//    every lane's accS col holds the full row-sum -> epilogue shfl reduce
//    deleted too. Denominator = sum of bf16 P == consistent with numerator.
//  - single P buffer per wave (reused across f; round-trip is within one
//    f-step, same dependency as R2) -> P addresses fully loop-invariant,
//    LDS 40 KiB -> 16 KiB.
// grid: pair = bid&31, head = (bid>>5)&7, qb = bid>>8 (0..3). 1024 blocks.
// ---------------------------------------------------------------------------
__global__ __launch_bounds__(256) void k_attn(const bf16* __restrict__ qk,
                                              const bf16* __restrict__ vT,
                                              bf16* __restrict__ o) {
    __shared__ __align__(16) bf16 klds[4 * 512];   // 4 KiB
    __shared__ __align__(16) bf16 vlds[4 * 512];   // 4 KiB
    __shared__ __align__(16) bf16 pl[4][1024];     // 8 KiB: per-wave 16x64 P, swizzled
    int bid = blockIdx.x;
    int pair = bid & 31, rest = bid >> 5;
    int head = rest & 7, qb = rest >> 3;  // qb 0..3
    int t = threadIdx.x, w = t >> 6, lane = t & 63, quad = lane >> 4, l16 = lane & 15;
    const bf16* qbp = qk + (size_t)pair * L_ * 512;
    // staging sources: wave w stages K chunk w and V chunk w
    const bf16* kg = qbp + (size_t)(l16 * 4 + w) * 512 + 256 + head * DH_ + quad * 8;
    const bf16* vg = vT + ((size_t)pair * C_ + head * DH_ + (w & 1) * 16 + l16) * L_
                        + (w >> 1) * 32 + quad * 8;
    bf16* kdst = &klds[w * 512];
    bf16* vdst = &vlds[w * 512];
    int qbase = qb * 256 + w * 64;
    // loop-invariant P-buffer addresses (hoisted once)
    char* pwb = (char*)&pl[w][0];
    char* pwr[4];
    const char* prd[2];
#pragma unroll
    for (int r = 0; r < 4; ++r) {
        int row = quad * 4 + r;
        pwr[r] = pwb + ((row * 128 + l16 * 8) ^ ((row & 7) << 4));
    }
#pragma unroll
    for (int ks = 0; ks < 2; ++ks)
        prd[ks] = pwb + ((l16 * 128 + ks * 64 + quad * 16) ^ ((l16 & 7) << 4));
    const bf16x8 ones = {(bf16)1.f, (bf16)1.f, (bf16)1.f, (bf16)1.f,
                         (bf16)1.f, (bf16)1.f, (bf16)1.f, (bf16)1.f};
    bf16x8 qf[4];
    f32x4 acc0[4], acc1[4], accS[4];
#pragma unroll
    for (int f = 0; f < 4; ++f) {
        qf[f] = ld8(qbp + (size_t)(qbase + f * 16 + l16) * 512 + head * DH_ + quad * 8);
        acc0[f] = (f32x4){0.f, 0.f, 0.f, 0.f};
        acc1[f] = (f32x4){0.f, 0.f, 0.f, 0.f};
        accS[f] = (f32x4){0.f, 0.f, 0.f, 0.f};
    }
    // prologue: stage tile 0
    stage16(kg, kdst);
    stage16(vg, vdst);
    __syncthreads();  // vmcnt drained -> tile 0 in LDS

    for (int kv0 = 0; kv0 < L_; kv0 += 64) {
        // pull tile's K/V fragments into regs (lane-linear -> conflict-free)
        bf16x8 kf[4], vf[4];
#pragma unroll
        for (int i = 0; i < 4; ++i) {
            kf[i] = ld8(&klds[(i * 64 + lane) * 8]);
            vf[i] = ld8(&vlds[(i * 64 + lane) * 8]);
        }
        __syncthreads();  // all waves consumed LDS K/V
        // stage tile t+1 (wraps harmlessly on last iter); latency hides under compute
        int kvn = (kv0 + 64) & (L_ - 1);
        stage16(kg + (size_t)kvn * 512, kdst);
        stage16(vg + kvn, vdst);
#pragma unroll
        for (int f = 0; f < 4; ++f) {
            f32x4 s[4];
#pragma unroll
            for (int kb = 0; kb < 4; ++kb)
                s[kb] = mfma16(qf[f], kf[kb], (f32x4){0.f, 0.f, 0.f, 0.f});
#pragma unroll
            for (int r = 0; r < 4; ++r) {
                float p0 = __builtin_amdgcn_exp2f(s[0][r]);
                float p1 = __builtin_amdgcn_exp2f(s[1][r]);
                float p2 = __builtin_amdgcn_exp2f(s[2][r]);
                float p3 = __builtin_amdgcn_exp2f(s[3][r]);
                bf16x4 pv = {(bf16)p0, (bf16)p1, (bf16)p2, (bf16)p3};
                *(bf16x4*)pwr[r] = pv;
            }
#pragma unroll
            for (int ks = 0; ks < 2; ++ks) {
                bf16x8 pf = *(const bf16x8*)prd[ks];
                acc0[f] = mfma16(pf, vf[ks * 2 + 0], acc0[f]);
                acc1[f] = mfma16(pf, vf[ks * 2 + 1], acc1[f]);
                accS[f] = mfma16(pf, ones, accS[f]);
            }
        }
        __syncthreads();  // vmcnt drained -> tile t+1 ready in LDS
    }
    bf16* orow = o + (size_t)pair * L_ * C_ + head * DH_;
#pragma unroll
    for (int f = 0; f < 4; ++f) {
#pragma unroll
        for (int r = 0; r < 4; ++r) {
            float inv = 1.f / accS[f][r];  // row-sum already in every lane
            int row = qbase + f * 16 + quad * 4 + r;
            orow[(size_t)row * C_ + l16]      = (bf16)(acc0[f][r] * inv);
            orow[(size_t)row * C_ + 16 + l16] = (bf16)(acc1[f][r] * inv);
        }
    }
}

// ---------------------------------------------------------------------------
// K3: y = LayerNorm(o @ W_out[a]^T + b_out[a] + xa) * gamma + beta  (bf16 out)
// m97-style staged GEMM: tile 128(M) x 256(N=full), BK=64, 4 waves 2x2,
// each wave 64x128 (4x8 frags). LN: shfl partials + LDS cross-wave combine.
// grid: 32 pair x 8 mt = 256
// ---------------------------------------------------------------------------
__global__ __launch_bounds__(256) void k_out(const bf16* __restrict__ o,
                                             const bf16* __restrict__ Wout,
                                             const float* __restrict__ bout,
                                             const bf16* __restrict__ xa,
                                             const float* __restrict__ gamma,
                                             const float* __restrict__ beta,
                                             bf16* __restrict__ y) {
    __shared__ __align__(16) bf16 lA[128 * 64];
    __shared__ __align__(16) bf16 lB[256 * 64];
    __shared__ float red[2][2][64][2];
    int bid = blockIdx.x;
    int mt = bid & 7, pair = bid >> 3;
    int a = pair & 3;
    int t = threadIdx.x, w = t >> 6, lane = t & 63;
    int wm = w >> 1, wn = w & 1;
    int quad = lane >> 4, l16 = lane & 15;
    int m0 = mt * 128;
    int r8 = lane >> 3, pc = lane & 7, jj = pc ^ r8;
    const bf16* ga = o + (size_t)pair * L_ * C_ + (size_t)(m0 + w * 32 + r8) * C_ + jj * 8;
    const bf16* gb = Wout + (size_t)a * C_ * C_ + (size_t)(w * 64 + r8) * C_ + jj * 8;
    f32x4 acc[4][8];
#pragma unroll
    for (int fm = 0; fm < 4; ++fm)
#pragma unroll
        for (int fn = 0; fn < 8; ++fn) acc[fm][fn] = (f32x4){0.f, 0.f, 0.f, 0.f};
    for (int k0 = 0; k0 < C_; k0 += 64) {
        __syncthreads();
#pragma unroll
        for (int i = 0; i < 4; ++i)
            stage16(ga + (size_t)(i * 8) * C_ + k0, lA + (w * 32 + i * 8) * 64);
#pragma unroll
        for (int i = 0; i < 8; ++i)
            stage16(gb + (size_t)(i * 8) * C_ + k0, lB + (w * 64 + i * 8) * 64);
        __syncthreads();
#pragma unroll
        for (int ks = 0; ks < 2; ++ks) {
            int p = (ks * 4 + quad) ^ (l16 & 7);
            bf16x8 am[4], bn[8];
#pragma unroll
            for (int f = 0; f < 4; ++f)
                am[f] = *(const bf16x8*)&lA[(wm * 64 + f * 16 + l16) * 64 + p * 8];
#pragma unroll
            for (int f = 0; f < 8; ++f)
                bn[f] = *(const bf16x8*)&lB[(wn * 128 + f * 16 + l16) * 64 + p * 8];
#pragma unroll
            for (int fm = 0; fm < 4; ++fm)
#pragma unroll
                for (int fn = 0; fn < 8; ++fn)
                    acc[fm][fn] = mfma16(am[fm], bn[fn], acc[fm][fn]);
        }
    }
    // bias + residual into acc
    const bf16* xb = xa + ((size_t)pair * L_ + m0 + wm * 64) * C_;
#pragma unroll
    for (int fn = 0; fn < 8; ++fn) {
        int col = wn * 128 + fn * 16 + l16;
        float bias = bout[a * C_ + col];
#pragma unroll
        for (int fm = 0; fm < 4; ++fm)
#pragma unroll
            for (int r = 0; r < 4; ++r)
                acc[fm][fn][r] += bias + (float)xb[(size_t)(fm * 16 + quad * 4 + r) * C_ + col];
    }
    // per-wave partial row sums -> LDS
#pragma unroll
    for (int fm = 0; fm < 4; ++fm) {
#pragma unroll
        for (int r = 0; r < 4; ++r) {
            float s1 = 0.f, s2 = 0.f;
#pragma unroll
            for (int fn = 0; fn < 8; ++fn) {
                float v = acc[fm][fn][r];
                s1 += v; s2 += v * v;
            }
#pragma unroll
            for (int off = 1; off < 16; off <<= 1) {
                s1 += __shfl_xor(s1, off);
                s2 += __shfl_xor(s2, off);
            }
            if (l16 == 0) {
                int rl = fm * 16 + quad * 4 + r;
                red[wm][wn][rl][0] = s1;
                red[wm][wn][rl][1] = s2;
            }
        }
    }
    __syncthreads();
    bf16* yb = y + ((size_t)pair * L_ + m0 + wm * 64) * C_;
#pragma unroll
    for (int fm = 0; fm < 4; ++fm) {
#pragma unroll
        for (int r = 0; r < 4; ++r) {
            int rl = fm * 16 + quad * 4 + r;
            float t1 = red[wm][0][rl][0] + red[wm][1][rl][0];
            float t2 = red[wm][0][rl][1] + red[wm][1][rl][1];
            float mu = t1 * (1.f / 256.f);
            float var = t2 * (1.f / 256.f) - mu * mu;
            float rstd = rsqrtf(var + 1e-5f);
#pragma unroll
            for (int fn = 0; fn < 8; ++fn) {
                int col = wn * 128 + fn * 16 + l16;
                yb[(size_t)rl * C_ + col] =
                    (bf16)((acc[fm][fn][r] - mu) * rstd * gamma[col] + beta[col]);
            }
        }
    }
}

// ---------------------------------------------------------------------------
// K4: y[pair, l, c] (bf16) -> out[B,C,H,W] (f32)
// ---------------------------------------------------------------------------
__global__ __launch_bounds__(256) void k_merge(const bf16* __restrict__ y,
                                               float* __restrict__ out) {
    __shared__ float lds[32][257];
    int bid = blockIdx.x;
    int pair = bid >> 5, p = bid & 31;
    int b = pair >> 2, a = pair & 3, i = a >> 1, j = a & 1;
    int t = threadIdx.x;
    int q = t & 31, csub = t >> 5;
    const bf16* yr = y + ((size_t)pair * L_ + (size_t)p * 32) * C_;
    for (int r = 0; r < 32; ++r) {
        lds[r][t] = (float)yr[(size_t)r * C_ + t];
    }
    __syncthreads();
    float* xb = out + (size_t)b * C_ * H_ * W_ + (size_t)(i * 32 + p) * W_ + j * 32;
    for (int r = 0; r < 32; ++r) {
        int c = r * 8 + csub;
        xb[(size_t)c * H_ * W_ + q] = lds[q][c];
    }
}

// ---------------------------------------------------------------------------
extern "C" void kernel_launch(void* const* d_in, const int* in_sizes, int n_in,
                              void* d_out, int out_size, void* d_ws, size_t ws_size,
                              hipStream_t stream) {
    (void)in_sizes; (void)n_in; (void)out_size; (void)ws_size;
    const float* x     = (const float*)d_in[0];
    const float* Win   = (const float*)d_in[1];
    const float* bin   = (const float*)d_in[2];
    const float* Wout  = (const float*)d_in[3];
    const float* bout  = (const float*)d_in[4];
    const float* gamma = (const float*)d_in[5];
    const float* beta  = (const float*)d_in[6];
    float* out = (float*)d_out;

    char* ws = (char*)d_ws;
    bf16* xa    = (bf16*)ws;                           // 16 MiB
    bf16* qk    = (bf16*)(ws + ((size_t)16 << 20));    // 32 MiB  [pair][L][512]
    bf16* vT    = (bf16*)(ws + ((size_t)48 << 20));    // 16 MiB  [pair][256][1024]
    bf16* o     = (bf16*)(ws + ((size_t)64 << 20));    // 16 MiB
    bf16* Winb  = (bf16*)(ws + ((size_t)80 << 20));    // 1.5 MiB
    bf16* Woutb = (bf16*)(ws + ((size_t)82 << 20));    // 0.5 MiB
    bf16* y     = (bf16*)(ws + ((size_t)16 << 20));    // 16 MiB, aliases dead qk

    k_split<<<NPAIR * 32 + 1024, 256, 0, stream>>>(x, xa, Win, Wout, Winb, Woutb);
    k_qkv<<<NPAIR * 8 * 6, 256, 0, stream>>>(xa, Winb, bin, qk, vT);
    k_attn<<<NPAIR * NH_ * 4, 256, 0, stream>>>(qk, vT, o);
    k_out<<<NPAIR * 8, 256, 0, stream>>>(o, Woutb, bout, xa, gamma, beta, y);
    k_merge<<<NPAIR * 32, 256, 0, stream>>>(y, out);
}

// Round 5
// 208.125 us; speedup vs baseline: 1.0869x; 1.0869x over previous
//
#include <hip/hip_runtime.h>
#include <cstdint>
#include <cstddef>

// Problem constants
#define B_    8
#define C_    256
#define H_    64
#define W_    64
#define A_    4
#define NH_   8
#define DH_   32
#define L_    1024
#define NPAIR 32
#define QKVN  768

typedef __bf16 bf16;
typedef __bf16 bf16x8 __attribute__((ext_vector_type(8)));
typedef __bf16 bf16x4 __attribute__((ext_vector_type(4)));
typedef float  f32x4  __attribute__((ext_vector_type(4)));

// dh^-0.5 * log2(e): folded into Q at projection time
#define QSCALE 0.25506866729736328f

__device__ inline f32x4 mfma16(bf16x8 a, bf16x8 b, f32x4 c) {
    return __builtin_amdgcn_mfma_f32_16x16x32_bf16(a, b, c, 0, 0, 0);
}
__device__ inline bf16x8 ld8(const bf16* p) { return *(const bf16x8*)p; }

// async global->LDS, 16B per lane; LDS dest = wave-uniform base + lane*16
__device__ inline void stage16(const bf16* g, bf16* l) {
    __builtin_amdgcn_global_load_lds(
        (const __attribute__((address_space(1))) void*)g,
        (__attribute__((address_space(3))) void*)l, 16, 0, 0);
}

// ---------------------------------------------------------------------------
// K0: fused  (a) x[B,C,H,W] f32 -> xa[pair,l,c] bf16   [blocks 0..1023]
//            (b) W_in/W_out f32 -> bf16 convert        [blocks 1024..2047]
// ---------------------------------------------------------------------------
#define NW4 (786432 / 4)
#define NO4 (262144 / 4)
__global__ __launch_bounds__(256) void k_split(const float* __restrict__ x,
                                               bf16* __restrict__ xa,
                                               const float* __restrict__ Win,
                                               const float* __restrict__ Wout,
                                               bf16* __restrict__ Winb,
                                               bf16* __restrict__ Woutb) {
    __shared__ float lds[32][257];
    int bid = blockIdx.x;
    int t = threadIdx.x;
    if (bid >= NPAIR * 32) {
        int tid = (bid - NPAIR * 32) * 256 + t;
        if (tid < NW4) {
            float4 v = ((const float4*)Win)[tid];
            bf16x4 ov = {(bf16)v.x, (bf16)v.y, (bf16)v.z, (bf16)v.w};
            ((bf16x4*)Winb)[tid] = ov;
        } else if (tid < NW4 + NO4) {
            int t2 = tid - NW4;
            float4 v = ((const float4*)Wout)[t2];
            bf16x4 ov = {(bf16)v.x, (bf16)v.y, (bf16)v.z, (bf16)v.w};
            ((bf16x4*)Woutb)[t2] = ov;
        }
        return;
    }
    int pair = bid >> 5, p = bid & 31;
    int b = pair >> 2, a = pair & 3, i = a >> 1, j = a & 1;
    int q = t & 31, csub = t >> 5;
    const float* xb = x + (size_t)b * C_ * H_ * W_ + (size_t)(i * 32 + p) * W_ + j * 32;
    for (int r = 0; r < 32; ++r) {
        int c = r * 8 + csub;
        lds[q][c] = xb[(size_t)c * H_ * W_ + q];
    }
    __syncthreads();
    bf16* xr = xa + ((size_t)pair * L_ + (size_t)p * 32) * C_;
    for (int r = 0; r < 32; ++r) {
        xr[(size_t)r * C_ + t] = (bf16)lds[r][t];
    }
}

// ---------------------------------------------------------------------------
// K1: in-projection, m97-style LDS-staged GEMM.
// Tile 128(M) x 128(N), BK=64, 4 waves 2x2, each wave 64x64 (4x4 frags).
// Epilogue: Q cols (<256) prescaled -> qk, K cols -> qk, V cols -> vT.
// grid: 32 pair x 8 mt x 6 nt = 1536
// ---------------------------------------------------------------------------
__global__ __launch_bounds__(256) void k_qkv(const bf16* __restrict__ xa,
                                             const bf16* __restrict__ Win,
                                             const float* __restrict__ bin,
                                             bf16* __restrict__ qk,
                                             bf16* __restrict__ vT) {
    __shared__ __align__(16) bf16 lA[128 * 64];
    __shared__ __align__(16) bf16 lB[128 * 64];
    int bid = blockIdx.x;
    int nt = bid % 6, mt = (bid / 6) & 7, pair = bid / 48;
    int a = pair & 3;
    int t = threadIdx.x, w = t >> 6, lane = t & 63;
    int wm = w >> 1, wn = w & 1;
    int quad = lane >> 4, l16 = lane & 15;
    int m0 = mt * 128, n0 = nt * 128;
    int r8 = lane >> 3, pc = lane & 7, jj = pc ^ r8;
    const bf16* ga = xa + (size_t)pair * L_ * C_ + (size_t)(m0 + w * 32 + r8) * C_ + jj * 8;
    const bf16* gb = Win + (size_t)a * QKVN * C_ + (size_t)(n0 + w * 32 + r8) * C_ + jj * 8;
    f32x4 acc[4][4];
#pragma unroll
    for (int fm = 0; fm < 4; ++fm)
#pragma unroll
        for (int fn = 0; fn < 4; ++fn) acc[fm][fn] = (f32x4){0.f, 0.f, 0.f, 0.f};
    for (int k0 = 0; k0 < C_; k0 += 64) {
        __syncthreads();
#pragma unroll
        for (int i = 0; i < 4; ++i) {
            stage16(ga + (size_t)(i * 8) * C_ + k0, lA + (w * 32 + i * 8) * 64);
            stage16(gb + (size_t)(i * 8) * C_ + k0, lB + (w * 32 + i * 8) * 64);
        }
        __syncthreads();
#pragma unroll
        for (int ks = 0; ks < 2; ++ks) {
            int p = (ks * 4 + quad) ^ (l16 & 7);
            bf16x8 am[4], bn[4];
#pragma unroll
            for (int f = 0; f < 4; ++f) {
                am[f] = *(const bf16x8*)&lA[(wm * 64 + f * 16 + l16) * 64 + p * 8];
                bn[f] = *(const bf16x8*)&lB[(wn * 64 + f * 16 + l16) * 64 + p * 8];
            }
#pragma unroll
            for (int fm = 0; fm < 4; ++fm)
#pragma unroll
                for (int fn = 0; fn < 4; ++fn)
                    acc[fm][fn] = mfma16(am[fm], bn[fn], acc[fm][fn]);
        }
    }
    int colbase = n0 + wn * 64;
    int mb = m0 + wm * 64;
    if (colbase < 512) {
        float sc = (colbase < 256) ? QSCALE : 1.0f;
        bf16* ob = qk + (size_t)pair * L_ * 512;
#pragma unroll
        for (int fn = 0; fn < 4; ++fn) {
            int col = colbase + fn * 16 + l16;
            float bias = bin[a * QKVN + col];
#pragma unroll
            for (int fm = 0; fm < 4; ++fm) {
                int m = mb + fm * 16 + quad * 4;
#pragma unroll
                for (int r = 0; r < 4; ++r)
                    ob[(size_t)(m + r) * 512 + col] = (bf16)((acc[fm][fn][r] + bias) * sc);
            }
        }
    } else {
        bf16* vb = vT + (size_t)pair * C_ * L_;
#pragma unroll
        for (int fn = 0; fn < 4; ++fn) {
            int e = colbase - 512 + fn * 16 + l16;
            float bias = bin[a * QKVN + colbase + fn * 16 + l16];
#pragma unroll
            for (int fm = 0; fm < 4; ++fm) {
                int m = mb + fm * 16 + quad * 4;
                bf16x4 pk = {(bf16)(acc[fm][fn][0] + bias), (bf16)(acc[fm][fn][1] + bias),
                             (bf16)(acc[fm][fn][2] + bias), (bf16)(acc[fm][fn][3] + bias)};
                *(bf16x4*)&vb[(size_t)e * L_ + m] = pk;
            }
        }
    }
}

// ---------------------------------------------------------------------------
// K2: attention. R2 structure EXACT (verified best: 67.7us).
// block 256 = 4 waves, same (pair, head); K/V staged once per block into LDS
// via global_load_lds (lane-linear layout -> conflict-free ds_read_b128);
// single-buffered, two __syncthreads per iter; next-tile stage issued right
// after frag reads so global latency hides under this block's compute.
// P buffer stride-64 + XOR swizzle -> 32 KiB; total LDS 40960 B = 4 blk/CU.
// grid: pair = bid&31, head = (bid>>5)&7, qb = bid>>8 (0..3). 1024 blocks.
// ---------------------------------------------------------------------------
__global__ __launch_bounds__(256) void k_attn(const bf16* __restrict__ qk,
                                              const bf16* __restrict__ vT,
                                              bf16* __restrict__ o) {
    __shared__ __align__(16) bf16 pl[4][4][1024];  // [wave][frag][16 rows x 64, swizzled]
    __shared__ __align__(16) bf16 klds[4 * 512];   // 4 KiB
    __shared__ __align__(16) bf16 vlds[4 * 512];   // 4 KiB
    int bid = blockIdx.x;
    int pair = bid & 31, rest = bid >> 5;
    int head = rest & 7, qb = rest >> 3;  // qb 0..3
    int t = threadIdx.x, w = t >> 6, lane = t & 63, quad = lane >> 4, l16 = lane & 15;
    const bf16* qbp = qk + (size_t)pair * L_ * 512;
    // staging sources: wave w stages K chunk kb=w and V chunk j=w
    const bf16* kg = qbp + (size_t)(l16 * 4 + w) * 512 + 256 + head * DH_ + quad * 8;
    const bf16* vg = vT + ((size_t)pair * C_ + head * DH_ + (w & 1) * 16 + l16) * L_
                        + (w >> 1) * 32 + quad * 8;
    bf16* kdst = &klds[w * 512];
    bf16* vdst = &vlds[w * 512];
    int qbase = qb * 256 + w * 64;
    bf16x8 qf[4];
    f32x4 acc0[4], acc1[4], l4[4];
#pragma unroll
    for (int f = 0; f < 4; ++f) {
        qf[f] = ld8(qbp + (size_t)(qbase + f * 16 + l16) * 512 + head * DH_ + quad * 8);
        acc0[f] = (f32x4){0.f, 0.f, 0.f, 0.f};
        acc1[f] = (f32x4){0.f, 0.f, 0.f, 0.f};
        l4[f]   = (f32x4){0.f, 0.f, 0.f, 0.f};
    }
    // prologue: stage tile 0
    stage16(kg, kdst);
    stage16(vg, vdst);
    __syncthreads();  // vmcnt drained -> tile 0 in LDS

    for (int kv0 = 0; kv0 < L_; kv0 += 64) {
        // pull tile's K/V fragments into regs (lane-linear -> conflict-free)
        bf16x8 kf[4], vf[4];
#pragma unroll
        for (int i = 0; i < 4; ++i) {
            kf[i] = ld8(&klds[(i * 64 + lane) * 8]);
            vf[i] = ld8(&vlds[(i * 64 + lane) * 8]);
        }
        __syncthreads();  // all waves consumed LDS K/V
        // stage tile t+1 (wraps harmlessly on last iter); latency hides under compute
        int kvn = (kv0 + 64) & (L_ - 1);
        stage16(kg + (size_t)kvn * 512, kdst);
        stage16(vg + kvn, vdst);
#pragma unroll
        for (int f = 0; f < 4; ++f) {
            f32x4 s[4];
#pragma unroll
            for (int kb = 0; kb < 4; ++kb) s[kb] = mfma16(qf[f], kf[kb], (f32x4){0.f, 0.f, 0.f, 0.f});
            char* pw = (char*)&pl[w][f][0];
#pragma unroll
            for (int r = 0; r < 4; ++r) {
                float p0 = __builtin_amdgcn_exp2f(s[0][r]);
                float p1 = __builtin_amdgcn_exp2f(s[1][r]);
                float p2 = __builtin_amdgcn_exp2f(s[2][r]);
                float p3 = __builtin_amdgcn_exp2f(s[3][r]);
                l4[f][r] += (p0 + p1) + (p2 + p3);
                bf16x4 pv = {(bf16)p0, (bf16)p1, (bf16)p2, (bf16)p3};
                int row = quad * 4 + r;
                int wo = (row * 128 + l16 * 8) ^ ((row & 7) << 4);
                *(bf16x4*)(pw + wo) = pv;
            }
#pragma unroll
            for (int ks = 0; ks < 2; ++ks) {
                int ro = (l16 * 128 + ks * 64 + quad * 16) ^ ((l16 & 7) << 4);
                bf16x8 pf = *(const bf16x8*)(pw + ro);
                acc0[f] = mfma16(pf, vf[ks * 2 + 0], acc0[f]);
                acc1[f] = mfma16(pf, vf[ks * 2 + 1], acc1[f]);
            }
        }
        __syncthreads();  // vmcnt drained -> tile t+1 ready in LDS
    }
    bf16* orow = o + (size_t)pair * L_ * C_ + head * DH_;
#pragma unroll
    for (int f = 0; f < 4; ++f) {
#pragma unroll
        for (int r = 0; r < 4; ++r) {
            float s1 = l4[f][r];
#pragma unroll
            for (int off = 1; off < 16; off <<= 1) s1 += __shfl_xor(s1, off);
            float inv = 1.f / s1;
            int row = qbase + f * 16 + quad * 4 + r;
            orow[(size_t)row * C_ + l16]      = (bf16)(acc0[f][r] * inv);
            orow[(size_t)row * C_ + 16 + l16] = (bf16)(acc1[f][r] * inv);
        }
    }
}

// ---------------------------------------------------------------------------
// K3: y = LayerNorm(o @ W_out[a]^T + b_out[a] + xa) * gamma + beta
//     FUSED with merge: writes out[B,C,H,W] f32 directly (k_merge removed).
// GEMM identical to before (tile 128x256, BK=64, 4 waves 2x2).
// Epilogue: normalize acc in place, then 4 chunks of 32 l-rows:
//   matching-wm waves write the 32x256 slab into padded f32 LDS (stride 258
//   -> <=2-way banks both phases), barrier, ALL threads emit coalesced
//   128B out segments (out[b][c][h][w]; each chunk is one h row).
// LDS: smem 48 KiB (GEMM lA+lB; transpose slab 33 KiB reuses it) + red 2 KiB.
// grid: 32 pair x 8 mt = 256
// ---------------------------------------------------------------------------
__global__ __launch_bounds__(256) void k_out(const bf16* __restrict__ o,
                                             const bf16* __restrict__ Wout,
                                             const float* __restrict__ bout,
                                             const bf16* __restrict__ xa,
                                             const float* __restrict__ gamma,
                                             const float* __restrict__ beta,
                                             float* __restrict__ out) {
    __shared__ __align__(16) char smem[49152];
    bf16* lA = (bf16*)smem;             // 128*64*2 = 16384
    bf16* lB = (bf16*)(smem + 16384);   // 256*64*2 = 32768
    float* tr = (float*)smem;           // 32*258*4 = 33024, reused post-GEMM
    __shared__ float red[2][2][64][2];
    int bid = blockIdx.x;
    int mt = bid & 7, pair = bid >> 3;
    int a = pair & 3;
    int t = threadIdx.x, w = t >> 6, lane = t & 63;
    int wm = w >> 1, wn = w & 1;
    int quad = lane >> 4, l16 = lane & 15;
    int m0 = mt * 128;
    int r8 = lane >> 3, pc = lane & 7, jj = pc ^ r8;
    const bf16* ga = o + (size_t)pair * L_ * C_ + (size_t)(m0 + w * 32 + r8) * C_ + jj * 8;
    const bf16* gb = Wout + (size_t)a * C_ * C_ + (size_t)(w * 64 + r8) * C_ + jj * 8;
    f32x4 acc[4][8];
#pragma unroll
    for (int fm = 0; fm < 4; ++fm)
#pragma unroll
        for (int fn = 0; fn < 8; ++fn) acc[fm][fn] = (f32x4){0.f, 0.f, 0.f, 0.f};
    for (int k0 = 0; k0 < C_; k0 += 64) {
        __syncthreads();
#pragma unroll
        for (int i = 0; i < 4; ++i)
            stage16(ga + (size_t)(i * 8) * C_ + k0, lA + (w * 32 + i * 8) * 64);
#pragma unroll
        for (int i = 0; i < 8; ++i)
            stage16(gb + (size_t)(i * 8) * C_ + k0, lB + (w * 64 + i * 8) * 64);
        __syncthreads();
#pragma unroll
        for (int ks = 0; ks < 2; ++ks) {
            int p = (ks * 4 + quad) ^ (l16 & 7);
            bf16x8 am[4], bn[8];
#pragma unroll
            for (int f = 0; f < 4; ++f)
                am[f] = *(const bf16x8*)&lA[(wm * 64 + f * 16 + l16) * 64 + p * 8];
#pragma unroll
            for (int f = 0; f < 8; ++f)
                bn[f] = *(const bf16x8*)&lB[(wn * 128 + f * 16 + l16) * 64 + p * 8];
#pragma unroll
            for (int fm = 0; fm < 4; ++fm)
#pragma unroll
                for (int fn = 0; fn < 8; ++fn)
                    acc[fm][fn] = mfma16(am[fm], bn[fn], acc[fm][fn]);
        }
    }
    // bias + residual into acc; hoist gamma/beta
    const bf16* xb = xa + ((size_t)pair * L_ + m0 + wm * 64) * C_;
    float g8[8], be8[8];
#pragma unroll
    for (int fn = 0; fn < 8; ++fn) {
        int col = wn * 128 + fn * 16 + l16;
        float bias = bout[a * C_ + col];
        g8[fn] = gamma[col];
        be8[fn] = beta[col];
#pragma unroll
        for (int fm = 0; fm < 4; ++fm)
#pragma unroll
            for (int r = 0; r < 4; ++r)
                acc[fm][fn][r] += bias + (float)xb[(size_t)(fm * 16 + quad * 4 + r) * C_ + col];
    }
    // per-wave partial row sums -> LDS
#pragma unroll
    for (int fm = 0; fm < 4; ++fm) {
#pragma unroll
        for (int r = 0; r < 4; ++r) {
            float s1 = 0.f, s2 = 0.f;
#pragma unroll
            for (int fn = 0; fn < 8; ++fn) {
                float v = acc[fm][fn][r];
                s1 += v; s2 += v * v;
            }
#pragma unroll
            for (int off = 1; off < 16; off <<= 1) {
                s1 += __shfl_xor(s1, off);
                s2 += __shfl_xor(s2, off);
            }
            if (l16 == 0) {
                int rl = fm * 16 + quad * 4 + r;
                red[wm][wn][rl][0] = s1;
                red[wm][wn][rl][1] = s2;
            }
        }
    }
    __syncthreads();  // red ready; also: all MFMA LDS reads done -> tr may reuse smem
    // normalize in place
#pragma unroll
    for (int fm = 0; fm < 4; ++fm) {
#pragma unroll
        for (int r = 0; r < 4; ++r) {
            int rl = fm * 16 + quad * 4 + r;
            float t1 = red[wm][0][rl][0] + red[wm][1][rl][0];
            float t2 = red[wm][0][rl][1] + red[wm][1][rl][1];
            float mu = t1 * (1.f / 256.f);
            float var = t2 * (1.f / 256.f) - mu * mu;
            float rstd = rsqrtf(var + 1e-5f);
#pragma unroll
            for (int fn = 0; fn < 8; ++fn)
                acc[fm][fn][r] = (acc[fm][fn][r] - mu) * rstd * g8[fn] + be8[fn];
        }
    }
    // fused merge: 4 chunks of 32 l-rows; each chunk = one h row of out
    int b = pair >> 2, i = (a >> 1), j = a & 1;
    int q = t & 31, csub = t >> 5;
    float* ob = out + (size_t)b * C_ * H_ * W_ + (size_t)(i * 32 + (m0 >> 5)) * W_ + j * 32;
#pragma unroll
    for (int ch = 0; ch < 4; ++ch) {
        __syncthreads();  // previous chunk's reads done before overwriting tr
        if (wm == (ch >> 1)) {
#pragma unroll
            for (int k = 0; k < 2; ++k) {
                int fm = (ch & 1) * 2 + k;
                int rb = (fm & 1) * 16 + quad * 4;
#pragma unroll
                for (int r = 0; r < 4; ++r)
#pragma unroll
                    for (int fn = 0; fn < 8; ++fn)
                        tr[(rb + r) * 258 + wn * 128 + fn * 16 + l16] = acc[fm][fn][r];
            }
        }
        __syncthreads();  // slab ready
#pragma unroll
        for (int r32 = 0; r32 < 32; ++r32) {
            int c = r32 * 8 + csub;
            ob[(size_t)c * (H_ * W_) + (size_t)ch * W_ + q] = tr[q * 258 + c];
        }
    }
}

// ---------------------------------------------------------------------------
extern "C" void kernel_launch(void* const* d_in, const int* in_sizes, int n_in,
                              void* d_out, int out_size, void* d_ws, size_t ws_size,
                              hipStream_t stream) {
    (void)in_sizes; (void)n_in; (void)out_size; (void)ws_size;
    const float* x     = (const float*)d_in[0];
    const float* Win   = (const float*)d_in[1];
    const float* bin   = (const float*)d_in[2];
    const float* Wout  = (const float*)d_in[3];
    const float* bout  = (const float*)d_in[4];
    const float* gamma = (const float*)d_in[5];
    const float* beta  = (const float*)d_in[6];
    float* out = (float*)d_out;

    char* ws = (char*)d_ws;
    bf16* xa    = (bf16*)ws;                           // 16 MiB
    bf16* qk    = (bf16*)(ws + ((size_t)16 << 20));    // 32 MiB  [pair][L][512]
    bf16* vT    = (bf16*)(ws + ((size_t)48 << 20));    // 16 MiB  [pair][256][1024]
    bf16* o     = (bf16*)(ws + ((size_t)64 << 20));    // 16 MiB
    bf16* Winb  = (bf16*)(ws + ((size_t)80 << 20));    // 1.5 MiB
    bf16* Woutb = (bf16*)(ws + ((size_t)82 << 20));    // 0.5 MiB

    k_split<<<NPAIR * 32 + 1024, 256, 0, stream>>>(x, xa, Win, Wout, Winb, Woutb);
    k_qkv<<<NPAIR * 8 * 6, 256, 0, stream>>>(xa, Winb, bin, qk, vT);
    k_attn<<<NPAIR * NH_ * 4, 256, 0, stream>>>(qk, vT, o);
    k_out<<<NPAIR * 8, 256, 0, stream>>>(o, Woutb, bout, xa, gamma, beta, out);
}

// Round 6
// 205.972 us; speedup vs baseline: 1.0983x; 1.0105x over previous
//
#include <hip/hip_runtime.h>
#include <cstdint>
#include <cstddef>

// Problem constants
#define B_    8
#define C_    256
#define H_    64
#define W_    64
#define A_    4
#define NH_   8
#define DH_   32
#define L_    1024
#define NPAIR 32
#define QKVN  768

typedef __bf16 bf16;
typedef __bf16 bf16x8 __attribute__((ext_vector_type(8)));
typedef __bf16 bf16x4 __attribute__((ext_vector_type(4)));
typedef float  f32x4  __attribute__((ext_vector_type(4)));

// dh^-0.5 * log2(e): folded into Q at projection time
#define QSCALE 0.25506866729736328f

__device__ inline f32x4 mfma16(bf16x8 a, bf16x8 b, f32x4 c) {
    return __builtin_amdgcn_mfma_f32_16x16x32_bf16(a, b, c, 0, 0, 0);
}
__device__ inline bf16x8 ld8(const bf16* p) { return *(const bf16x8*)p; }

// async global->LDS, 16B per lane; LDS dest = wave-uniform base + lane*16
__device__ inline void stage16(const bf16* g, bf16* l) {
    __builtin_amdgcn_global_load_lds(
        (const __attribute__((address_space(1))) void*)g,
        (__attribute__((address_space(3))) void*)l, 16, 0, 0);
}

// ---------------------------------------------------------------------------
// K0: fused  (a) x[B,C,H,W] f32 -> xa[pair,l,c] bf16   [blocks 0..1023]
//            (b) W_in/W_out f32 -> bf16 convert        [blocks 1024..2047]
// ---------------------------------------------------------------------------
#define NW4 (786432 / 4)
#define NO4 (262144 / 4)
__global__ __launch_bounds__(256) void k_split(const float* __restrict__ x,
                                               bf16* __restrict__ xa,
                                               const float* __restrict__ Win,
                                               const float* __restrict__ Wout,
                                               bf16* __restrict__ Winb,
                                               bf16* __restrict__ Woutb) {
    __shared__ float lds[32][257];
    int bid = blockIdx.x;
    int t = threadIdx.x;
    if (bid >= NPAIR * 32) {
        int tid = (bid - NPAIR * 32) * 256 + t;
        if (tid < NW4) {
            float4 v = ((const float4*)Win)[tid];
            bf16x4 ov = {(bf16)v.x, (bf16)v.y, (bf16)v.z, (bf16)v.w};
            ((bf16x4*)Winb)[tid] = ov;
        } else if (tid < NW4 + NO4) {
            int t2 = tid - NW4;
            float4 v = ((const float4*)Wout)[t2];
            bf16x4 ov = {(bf16)v.x, (bf16)v.y, (bf16)v.z, (bf16)v.w};
            ((bf16x4*)Woutb)[t2] = ov;
        }
        return;
    }
    int pair = bid >> 5, p = bid & 31;
    int b = pair >> 2, a = pair & 3, i = a >> 1, j = a & 1;
    int q = t & 31, csub = t >> 5;
    const float* xb = x + (size_t)b * C_ * H_ * W_ + (size_t)(i * 32 + p) * W_ + j * 32;
    for (int r = 0; r < 32; ++r) {
        int c = r * 8 + csub;
        lds[q][c] = xb[(size_t)c * H_ * W_ + q];
    }
    __syncthreads();
    bf16* xr = xa + ((size_t)pair * L_ + (size_t)p * 32) * C_;
    for (int r = 0; r < 32; ++r) {
        xr[(size_t)r * C_ + t] = (bf16)lds[r][t];
    }
}

// ---------------------------------------------------------------------------
// K1: in-projection, m97-style LDS-staged GEMM.
// Tile 128(M) x 128(N), BK=64, 4 waves 2x2, each wave 64x64 (4x4 frags).
// Epilogue: Q cols (<256) prescaled -> qk, K cols -> qk, V cols -> vT.
// grid: 32 pair x 8 mt x 6 nt = 1536
// ---------------------------------------------------------------------------
__global__ __launch_bounds__(256) void k_qkv(const bf16* __restrict__ xa,
                                             const bf16* __restrict__ Win,
                                             const float* __restrict__ bin,
                                             bf16* __restrict__ qk,
                                             bf16* __restrict__ vT) {
    __shared__ __align__(16) bf16 lA[128 * 64];
    __shared__ __align__(16) bf16 lB[128 * 64];
    int bid = blockIdx.x;
    int nt = bid % 6, mt = (bid / 6) & 7, pair = bid / 48;
    int a = pair & 3;
    int t = threadIdx.x, w = t >> 6, lane = t & 63;
    int wm = w >> 1, wn = w & 1;
    int quad = lane >> 4, l16 = lane & 15;
    int m0 = mt * 128, n0 = nt * 128;
    int r8 = lane >> 3, pc = lane & 7, jj = pc ^ r8;
    const bf16* ga = xa + (size_t)pair * L_ * C_ + (size_t)(m0 + w * 32 + r8) * C_ + jj * 8;
    const bf16* gb = Win + (size_t)a * QKVN * C_ + (size_t)(n0 + w * 32 + r8) * C_ + jj * 8;
    f32x4 acc[4][4];
#pragma unroll
    for (int fm = 0; fm < 4; ++fm)
#pragma unroll
        for (int fn = 0; fn < 4; ++fn) acc[fm][fn] = (f32x4){0.f, 0.f, 0.f, 0.f};
    for (int k0 = 0; k0 < C_; k0 += 64) {
        __syncthreads();
#pragma unroll
        for (int i = 0; i < 4; ++i) {
            stage16(ga + (size_t)(i * 8) * C_ + k0, lA + (w * 32 + i * 8) * 64);
            stage16(gb + (size_t)(i * 8) * C_ + k0, lB + (w * 32 + i * 8) * 64);
        }
        __syncthreads();
#pragma unroll
        for (int ks = 0; ks < 2; ++ks) {
            int p = (ks * 4 + quad) ^ (l16 & 7);
            bf16x8 am[4], bn[4];
#pragma unroll
            for (int f = 0; f < 4; ++f) {
                am[f] = *(const bf16x8*)&lA[(wm * 64 + f * 16 + l16) * 64 + p * 8];
                bn[f] = *(const bf16x8*)&lB[(wn * 64 + f * 16 + l16) * 64 + p * 8];
            }
#pragma unroll
            for (int fm = 0; fm < 4; ++fm)
#pragma unroll
                for (int fn = 0; fn < 4; ++fn)
                    acc[fm][fn] = mfma16(am[fm], bn[fn], acc[fm][fn]);
        }
    }
    int colbase = n0 + wn * 64;
    int mb = m0 + wm * 64;
    if (colbase < 512) {
        float sc = (colbase < 256) ? QSCALE : 1.0f;
        bf16* ob = qk + (size_t)pair * L_ * 512;
#pragma unroll
        for (int fn = 0; fn < 4; ++fn) {
            int col = colbase + fn * 16 + l16;
            float bias = bin[a * QKVN + col];
#pragma unroll
            for (int fm = 0; fm < 4; ++fm) {
                int m = mb + fm * 16 + quad * 4;
#pragma unroll
                for (int r = 0; r < 4; ++r)
                    ob[(size_t)(m + r) * 512 + col] = (bf16)((acc[fm][fn][r] + bias) * sc);
            }
        }
    } else {
        bf16* vb = vT + (size_t)pair * C_ * L_;
#pragma unroll
        for (int fn = 0; fn < 4; ++fn) {
            int e = colbase - 512 + fn * 16 + l16;
            float bias = bin[a * QKVN + colbase + fn * 16 + l16];
#pragma unroll
            for (int fm = 0; fm < 4; ++fm) {
                int m = mb + fm * 16 + quad * 4;
                bf16x4 pk = {(bf16)(acc[fm][fn][0] + bias), (bf16)(acc[fm][fn][1] + bias),
                             (bf16)(acc[fm][fn][2] + bias), (bf16)(acc[fm][fn][3] + bias)};
                *(bf16x4*)&vb[(size_t)e * L_ + m] = pk;
            }
        }
    }
}

// ---------------------------------------------------------------------------
// K2: attention. R6: occupancy doubling. Inner loop is R2-verbatim; the only
// changes are the work partition and LDS footprint:
//  - qb split 4 -> 8 (grid 2048): each wave owns 2 Q-frags (32 rows), so
//    persistent state halves (qf 8 + acc 16 + l4 8 = 32 VGPR) -> target
//    VGPR <= 64 -> 8 waves/SIMD (32 waves/CU, 2x TLP for latency hiding).
//  - single P buffer per wave (R4-proven safe): LDS = 4+4+8 = 16 KiB ->
//    LDS allows 10 blocks/CU; wave cap gives 8 blocks/CU.
//  - 8 blocks now share each (pair,head) K/V; bid stride 256 == 0 mod 8
//    keeps sharers on one XCD (L2-local).
// grid: pair = bid&31, head = (bid>>5)&7, qb = bid>>8 (0..7). 2048 blocks.
// ---------------------------------------------------------------------------
__global__ __launch_bounds__(256) void k_attn(const bf16* __restrict__ qk,
                                              const bf16* __restrict__ vT,
                                              bf16* __restrict__ o) {
    __shared__ __align__(16) bf16 pl[4][1024];     // per-wave 16x64 P, swizzled (8 KiB)
    __shared__ __align__(16) bf16 klds[4 * 512];   // 4 KiB
    __shared__ __align__(16) bf16 vlds[4 * 512];   // 4 KiB
    int bid = blockIdx.x;
    int pair = bid & 31, rest = bid >> 5;
    int head = rest & 7, qb = rest >> 3;  // qb 0..7
    int t = threadIdx.x, w = t >> 6, lane = t & 63, quad = lane >> 4, l16 = lane & 15;
    const bf16* qbp = qk + (size_t)pair * L_ * 512;
    // staging sources: wave w stages K chunk w and V chunk w (R2-identical)
    const bf16* kg = qbp + (size_t)(l16 * 4 + w) * 512 + 256 + head * DH_ + quad * 8;
    const bf16* vg = vT + ((size_t)pair * C_ + head * DH_ + (w & 1) * 16 + l16) * L_
                        + (w >> 1) * 32 + quad * 8;
    bf16* kdst = &klds[w * 512];
    bf16* vdst = &vlds[w * 512];
    int qbase = qb * 128 + w * 32;
    bf16x8 qf[2];
    f32x4 acc0[2], acc1[2], l4[2];
#pragma unroll
    for (int f = 0; f < 2; ++f) {
        qf[f] = ld8(qbp + (size_t)(qbase + f * 16 + l16) * 512 + head * DH_ + quad * 8);
        acc0[f] = (f32x4){0.f, 0.f, 0.f, 0.f};
        acc1[f] = (f32x4){0.f, 0.f, 0.f, 0.f};
        l4[f]   = (f32x4){0.f, 0.f, 0.f, 0.f};
    }
    // prologue: stage tile 0
    stage16(kg, kdst);
    stage16(vg, vdst);
    __syncthreads();  // vmcnt drained -> tile 0 in LDS

    for (int kv0 = 0; kv0 < L_; kv0 += 64) {
        // pull tile's K/V fragments into regs (lane-linear -> conflict-free)
        bf16x8 kf[4], vf[4];
#pragma unroll
        for (int i = 0; i < 4; ++i) {
            kf[i] = ld8(&klds[(i * 64 + lane) * 8]);
            vf[i] = ld8(&vlds[(i * 64 + lane) * 8]);
        }
        __syncthreads();  // all waves consumed LDS K/V
        // stage tile t+1 (wraps harmlessly on last iter); latency hides under compute
        int kvn = (kv0 + 64) & (L_ - 1);
        stage16(kg + (size_t)kvn * 512, kdst);
        stage16(vg + kvn, vdst);
#pragma unroll
        for (int f = 0; f < 2; ++f) {
            f32x4 s[4];
#pragma unroll
            for (int kb = 0; kb < 4; ++kb) s[kb] = mfma16(qf[f], kf[kb], (f32x4){0.f, 0.f, 0.f, 0.f});
            char* pw = (char*)&pl[w][0];
#pragma unroll
            for (int r = 0; r < 4; ++r) {
                float p0 = __builtin_amdgcn_exp2f(s[0][r]);
                float p1 = __builtin_amdgcn_exp2f(s[1][r]);
                float p2 = __builtin_amdgcn_exp2f(s[2][r]);
                float p3 = __builtin_amdgcn_exp2f(s[3][r]);
                l4[f][r] += (p0 + p1) + (p2 + p3);
                bf16x4 pv = {(bf16)p0, (bf16)p1, (bf16)p2, (bf16)p3};
                int row = quad * 4 + r;
                int wo = (row * 128 + l16 * 8) ^ ((row & 7) << 4);
                *(bf16x4*)(pw + wo) = pv;
            }
#pragma unroll
            for (int ks = 0; ks < 2; ++ks) {
                int ro = (l16 * 128 + ks * 64 + quad * 16) ^ ((l16 & 7) << 4);
                bf16x8 pf = *(const bf16x8*)(pw + ro);
                acc0[f] = mfma16(pf, vf[ks * 2 + 0], acc0[f]);
                acc1[f] = mfma16(pf, vf[ks * 2 + 1], acc1[f]);
            }
        }
        __syncthreads();  // vmcnt drained -> tile t+1 ready in LDS
    }
    bf16* orow = o + (size_t)pair * L_ * C_ + head * DH_;
#pragma unroll
    for (int f = 0; f < 2; ++f) {
#pragma unroll
        for (int r = 0; r < 4; ++r) {
            float s1 = l4[f][r];
#pragma unroll
            for (int off = 1; off < 16; off <<= 1) s1 += __shfl_xor(s1, off);
            float inv = 1.f / s1;
            int row = qbase + f * 16 + quad * 4 + r;
            orow[(size_t)row * C_ + l16]      = (bf16)(acc0[f][r] * inv);
            orow[(size_t)row * C_ + 16 + l16] = (bf16)(acc1[f][r] * inv);
        }
    }
}

// ---------------------------------------------------------------------------
// K3: y = LayerNorm(o @ W_out[a]^T + b_out[a] + xa) * gamma + beta
//     FUSED with merge: writes out[B,C,H,W] f32 directly.
// GEMM tile 128x256, BK=64, 4 waves 2x2. Epilogue: normalize in place, then
// 4 chunks of {32x256 slab -> padded f32 LDS (stride 258), barrier,
// coalesced 128B out segments}. grid: 32 pair x 8 mt = 256
// ---------------------------------------------------------------------------
__global__ __launch_bounds__(256) void k_out(const bf16* __restrict__ o,
                                             const bf16* __restrict__ Wout,
                                             const float* __restrict__ bout,
                                             const bf16* __restrict__ xa,
                                             const float* __restrict__ gamma,
                                             const float* __restrict__ beta,
                                             float* __restrict__ out) {
    __shared__ __align__(16) char smem[49152];
    bf16* lA = (bf16*)smem;             // 128*64*2 = 16384
    bf16* lB = (bf16*)(smem + 16384);   // 256*64*2 = 32768
    float* tr = (float*)smem;           // 32*258*4 = 33024, reused post-GEMM
    __shared__ float red[2][2][64][2];
    int bid = blockIdx.x;
    int mt = bid & 7, pair = bid >> 3;
    int a = pair & 3;
    int t = threadIdx.x, w = t >> 6, lane = t & 63;
    int wm = w >> 1, wn = w & 1;
    int quad = lane >> 4, l16 = lane & 15;
    int m0 = mt * 128;
    int r8 = lane >> 3, pc = lane & 7, jj = pc ^ r8;
    const bf16* ga = o + (size_t)pair * L_ * C_ + (size_t)(m0 + w * 32 + r8) * C_ + jj * 8;
    const bf16* gb = Wout + (size_t)a * C_ * C_ + (size_t)(w * 64 + r8) * C_ + jj * 8;
    f32x4 acc[4][8];
#pragma unroll
    for (int fm = 0; fm < 4; ++fm)
#pragma unroll
        for (int fn = 0; fn < 8; ++fn) acc[fm][fn] = (f32x4){0.f, 0.f, 0.f, 0.f};
    for (int k0 = 0; k0 < C_; k0 += 64) {
        __syncthreads();
#pragma unroll
        for (int i = 0; i < 4; ++i)
            stage16(ga + (size_t)(i * 8) * C_ + k0, lA + (w * 32 + i * 8) * 64);
#pragma unroll
        for (int i = 0; i < 8; ++i)
            stage16(gb + (size_t)(i * 8) * C_ + k0, lB + (w * 64 + i * 8) * 64);
        __syncthreads();
#pragma unroll
        for (int ks = 0; ks < 2; ++ks) {
            int p = (ks * 4 + quad) ^ (l16 & 7);
            bf16x8 am[4], bn[8];
#pragma unroll
            for (int f = 0; f < 4; ++f)
                am[f] = *(const bf16x8*)&lA[(wm * 64 + f * 16 + l16) * 64 + p * 8];
#pragma unroll
            for (int f = 0; f < 8; ++f)
                bn[f] = *(const bf16x8*)&lB[(wn * 128 + f * 16 + l16) * 64 + p * 8];
#pragma unroll
            for (int fm = 0; fm < 4; ++fm)
#pragma unroll
                for (int fn = 0; fn < 8; ++fn)
                    acc[fm][fn] = mfma16(am[fm], bn[fn], acc[fm][fn]);
        }
    }
    // bias + residual into acc; hoist gamma/beta
    const bf16* xb = xa + ((size_t)pair * L_ + m0 + wm * 64) * C_;
    float g8[8], be8[8];
#pragma unroll
    for (int fn = 0; fn < 8; ++fn) {
        int col = wn * 128 + fn * 16 + l16;
        float bias = bout[a * C_ + col];
        g8[fn] = gamma[col];
        be8[fn] = beta[col];
#pragma unroll
        for (int fm = 0; fm < 4; ++fm)
#pragma unroll
            for (int r = 0; r < 4; ++r)
                acc[fm][fn][r] += bias + (float)xb[(size_t)(fm * 16 + quad * 4 + r) * C_ + col];
    }
    // per-wave partial row sums -> LDS
#pragma unroll
    for (int fm = 0; fm < 4; ++fm) {
#pragma unroll
        for (int r = 0; r < 4; ++r) {
            float s1 = 0.f, s2 = 0.f;
#pragma unroll
            for (int fn = 0; fn < 8; ++fn) {
                float v = acc[fm][fn][r];
                s1 += v; s2 += v * v;
            }
#pragma unroll
            for (int off = 1; off < 16; off <<= 1) {
                s1 += __shfl_xor(s1, off);
                s2 += __shfl_xor(s2, off);
            }
            if (l16 == 0) {
                int rl = fm * 16 + quad * 4 + r;
                red[wm][wn][rl][0] = s1;
                red[wm][wn][rl][1] = s2;
            }
        }
    }
    __syncthreads();  // red ready; also: all MFMA LDS reads done -> tr may reuse smem
    // normalize in place
#pragma unroll
    for (int fm = 0; fm < 4; ++fm) {
#pragma unroll
        for (int r = 0; r < 4; ++r) {
            int rl = fm * 16 + quad * 4 + r;
            float t1 = red[wm][0][rl][0] + red[wm][1][rl][0];
            float t2 = red[wm][0][rl][1] + red[wm][1][rl][1];
            float mu = t1 * (1.f / 256.f);
            float var = t2 * (1.f / 256.f) - mu * mu;
            float rstd = rsqrtf(var + 1e-5f);
#pragma unroll
            for (int fn = 0; fn < 8; ++fn)
                acc[fm][fn][r] = (acc[fm][fn][r] - mu) * rstd * g8[fn] + be8[fn];
        }
    }
    // fused merge: 4 chunks of 32 l-rows; each chunk = one h row of out
    int b = pair >> 2, i = (a >> 1), j = a & 1;
    int q = t & 31, csub = t >> 5;
    float* ob = out + (size_t)b * C_ * H_ * W_ + (size_t)(i * 32 + (m0 >> 5)) * W_ + j * 32;
#pragma unroll
    for (int ch = 0; ch < 4; ++ch) {
        __syncthreads();  // previous chunk's reads done before overwriting tr
        if (wm == (ch >> 1)) {
#pragma unroll
            for (int k = 0; k < 2; ++k) {
                int fm = (ch & 1) * 2 + k;
                int rb = (fm & 1) * 16 + quad * 4;
#pragma unroll
                for (int r = 0; r < 4; ++r)
#pragma unroll
                    for (int fn = 0; fn < 8; ++fn)
                        tr[(rb + r) * 258 + wn * 128 + fn * 16 + l16] = acc[fm][fn][r];
            }
        }
        __syncthreads();  // slab ready
#pragma unroll
        for (int r32 = 0; r32 < 32; ++r32) {
            int c = r32 * 8 + csub;
            ob[(size_t)c * (H_ * W_) + (size_t)ch * W_ + q] = tr[q * 258 + c];
        }
    }
}

// ---------------------------------------------------------------------------
extern "C" void kernel_launch(void* const* d_in, const int* in_sizes, int n_in,
                              void* d_out, int out_size, void* d_ws, size_t ws_size,
                              hipStream_t stream) {
    (void)in_sizes; (void)n_in; (void)out_size; (void)ws_size;
    const float* x     = (const float*)d_in[0];
    const float* Win   = (const float*)d_in[1];
    const float* bin   = (const float*)d_in[2];
    const float* Wout  = (const float*)d_in[3];
    const float* bout  = (const float*)d_in[4];
    const float* gamma = (const float*)d_in[5];
    const float* beta  = (const float*)d_in[6];
    float* out = (float*)d_out;

    char* ws = (char*)d_ws;
    bf16* xa    = (bf16*)ws;                           // 16 MiB
    bf16* qk    = (bf16*)(ws + ((size_t)16 << 20));    // 32 MiB  [pair][L][512]
    bf16* vT    = (bf16*)(ws + ((size_t)48 << 20));    // 16 MiB  [pair][256][1024]
    bf16* o     = (bf16*)(ws + ((size_t)64 << 20));    // 16 MiB
    bf16* Winb  = (bf16*)(ws + ((size_t)80 << 20));    // 1.5 MiB
    bf16* Woutb = (bf16*)(ws + ((size_t)82 << 20));    // 0.5 MiB

    k_split<<<NPAIR * 32 + 1024, 256, 0, stream>>>(x, xa, Win, Wout, Winb, Woutb);
    k_qkv<<<NPAIR * 8 * 6, 256, 0, stream>>>(xa, Winb, bin, qk, vT);
    k_attn<<<NPAIR * NH_ * 8, 256, 0, stream>>>(qk, vT, o);
    k_out<<<NPAIR * 8, 256, 0, stream>>>(o, Woutb, bout, xa, gamma, beta, out);
}